// Round 4
// baseline (98.729 us; speedup 1.0000x reference)
//
#include <hip/hip_runtime.h>
#include <math.h>
#include <limits.h>

#define SIZE   256
#define NFACES 256
#define NVERTS 1024
#define NSPLIT 4
#define PFSZ   20   // floats per face record (80 B, 16B-aligned)

// record layout (floats):
// 0 ax 1 ay 2 bx 3 by 4 cx 5 cy | 6 z0i 7 z1i 8 z2i |
// 9 u0x 10 u0y 11 u1x 12 u1y 13 u2x 14 u2y | 15 A | 16 xmin 17 xmax | 18,19 pad

// ws layout (bytes):
//   0      : float fdG[256*20]   (20480 B)
//   20480  : float zinit
//   20544  : int   rowPtr[257]
//   22528  : int   ids[...]      (worst case 65536 ints)

// ---------------- prep: one block, 256 threads (thread t = face t) ----------
__global__ __launch_bounds__(256) void prep_kernel(
    const float* __restrict__ vertices,  // (1024,3)
    const int*   __restrict__ faces,     // (256,3)
    const float* __restrict__ uv,        // (1024,2)
    const int*   __restrict__ uvfaces,   // (256,3)
    float* __restrict__ fdG, float* __restrict__ zinitp,
    int* __restrict__ rowPtr, int* __restrict__ ids)
{
#pragma clang fp contract(off)
    __shared__ int   scnt[256];
    __shared__ int   sscan[256];
    __shared__ int   soff[256];
    __shared__ float wred[4];

    const int t    = threadIdx.x;
    const int lane = t & 63;
    const int wv   = t >> 6;

    // zinit = min over 1024 vertex z
    {
        float m = fminf(fminf(vertices[3*t+2],       vertices[3*(t+256)+2]),
                        fminf(vertices[3*(t+512)+2], vertices[3*(t+768)+2]));
        for (int off = 32; off > 0; off >>= 1) m = fminf(m, __shfl_down(m, off));
        if (lane == 0) wred[wv] = m;
    }
    scnt[t] = 0;

    // per-face record
    const int i0 = faces[3*t+0], i1 = faces[3*t+1], i2 = faces[3*t+2];
    const float ax = vertices[3*i0+0], ay = vertices[3*i0+1], az = vertices[3*i0+2];
    const float bx = vertices[3*i1+0], by = vertices[3*i1+1], bz = vertices[3*i1+2];
    const float cx = vertices[3*i2+0], cy = vertices[3*i2+1], cz = vertices[3*i2+2];
    // A = area2d; same fp32 expression as face-normal z, so
    // cullmask & (A>=1e-9) == (A>=1e-9); A>=1e-9 also => Asafe==A
    const float A = (bx-ax)*(cy-ay) - (by-ay)*(cx-ax);
    const float z0i = 1.0f/az, z1i = 1.0f/bz, z2i = 1.0f/cz;
    const int j0 = uvfaces[3*t+0], j1 = uvfaces[3*t+1], j2 = uvfaces[3*t+2];
    float* r = &fdG[t*PFSZ];
    r[0]=ax; r[1]=ay; r[2]=bx; r[3]=by; r[4]=cx; r[5]=cy;
    r[6]=z0i; r[7]=z1i; r[8]=z2i;
    r[9]  = (uv[2*j0+0]*2.0f - 1.0f) * z0i;
    r[10] = (uv[2*j0+1]*2.0f - 1.0f) * z0i;
    r[11] = (uv[2*j1+0]*2.0f - 1.0f) * z1i;
    r[12] = (uv[2*j1+1]*2.0f - 1.0f) * z1i;
    r[13] = (uv[2*j2+0]*2.0f - 1.0f) * z2i;
    r[14] = (uv[2*j2+1]*2.0f - 1.0f) * z2i;
    r[15] = A;
    r[16] = fminf(fminf(ax,bx),cx);   // xmin
    r[17] = fmaxf(fmaxf(ax,bx),cx);   // xmax
    r[18] = 0.0f; r[19] = 0.0f;

    // conservative row range: py(row) = 1 - row*(2/255); 1e-4 margin + 1-row slack
    const float ymin = fminf(fminf(ay,by),cy);
    const float ymax = fmaxf(fmaxf(ay,by),cy);
    const bool keep = (A >= 1e-9f);
    int r_lo = 0, r_hi = -1;
    if (keep) {
        r_lo = (int)floor((1.0 - ((double)ymax + 1e-4)) * 127.5) - 1;
        r_hi = (int)ceil ((1.0 - ((double)ymin - 1e-4)) * 127.5) + 1;
        if (r_lo < 0)   r_lo = 0;
        if (r_hi > 255) r_hi = 255;
    }
    __syncthreads();   // scnt zeroed, wred published

    if (t == 0) zinitp[0] = fminf(fminf(wred[0],wred[1]), fminf(wred[2],wred[3]));

    for (int rr = r_lo; rr <= r_hi; ++rr) atomicAdd(&scnt[rr], 1);
    __syncthreads();

    // inclusive Hillis-Steele scan of scnt -> sscan
    sscan[t] = scnt[t];
    __syncthreads();
    for (int s = 1; s < 256; s <<= 1) {
        const int add = (t >= s) ? sscan[t - s] : 0;
        __syncthreads();
        sscan[t] += add;
        __syncthreads();
    }
    rowPtr[t+1] = sscan[t];
    if (t == 0) rowPtr[0] = 0;
    soff[t] = sscan[t] - scnt[t];    // exclusive start
    __syncthreads();

    for (int rr = r_lo; rr <= r_hi; ++rr) {
        const int pos = atomicAdd(&soff[rr], 1);
        ids[pos] = t;                // order within a row is arbitrary (tie-break by fid)
    }
}

// ---------------- raster: 256 blocks (rows) x 1024 threads ------------------
__global__ __launch_bounds__(1024) void raster_kernel(
    const float* __restrict__ fdG, const float* __restrict__ zinitp,
    const int* __restrict__ rowPtr, const int* __restrict__ ids,
    const float* __restrict__ uvmap,     // (3,256,256)
    float* __restrict__ out)             // (4,256,256)
{
#pragma clang fp contract(off)
    __shared__ float fdl[NFACES * PFSZ];
    __shared__ int   sfid[NFACES];
    __shared__ float sh_best[NSPLIT][256];
    __shared__ int   sh_fid [NSPLIT][256];
    __shared__ int   sh_slot[NSPLIT][256];

    const int t   = threadIdx.x;
    const int col = t & 255;
    const int grp = t >> 8;     // 0..3
    const int row = blockIdx.x;

    const int base = rowPtr[row];
    const int nv   = rowPtr[row+1] - base;
    const float zinit = zinitp[0];

    // stage this row's pre-culled faces into LDS (80 B each, coalesced float4)
    for (int i = t; i < nv; i += 1024) {
        const int f = ids[base + i];
        sfid[i] = f;
        const float4* src = (const float4*)&fdG[f * PFSZ];
        float4*       dst = (float4*)&fdl[i * PFSZ];
        dst[0] = src[0]; dst[1] = src[1]; dst[2] = src[2]; dst[3] = src[3]; dst[4] = src[4];
    }
    __syncthreads();

    // pts[i,j] = (lin[j], lin[255-i]); linspace f64 -> f32 (numpy style)
    const float px = (float)(-1.0 + (double)col         * (2.0/255.0));
    const float py = (float)(-1.0 + (double)(255 - row) * (2.0/255.0));

    // wave-uniform x-span (each wave = 64 contiguous columns)
    const int   c0   = ((t >> 6) & 3) * 64;
    const float pxlo = (float)(-1.0 + (double)c0        * (2.0/255.0));
    const float pxhi = (float)(-1.0 + (double)(c0 + 63) * (2.0/255.0));

    const int cs = (nv + NSPLIT - 1) / NSPLIT;
    int f0 = grp * cs; if (f0 > nv) f0 = nv;
    int f1 = f0 + cs;  if (f1 > nv) f1 = nv;

    float best = -INFINITY;
    int   wfid = INT_MAX;
    int   wslot = 0;
    for (int i = f0; i < f1; ++i) {
        const float* c = &fdl[i * PFSZ];
        // wave-uniform x-bbox cull, same 1e-4 margin argument as the row cull
        if (c[17] + 1e-4f < pxlo || c[16] - 1e-4f > pxhi) continue;
        const float pAB = (px - c[2])*(c[1] - c[3]) - (py - c[3])*(c[0] - c[2]);
        const float pCB = (px - c[4])*(c[3] - c[5]) - (py - c[5])*(c[2] - c[4]);
        const float pCA = (px - c[0])*(c[5] - c[1]) - (py - c[1])*(c[4] - c[0]);
        if (pAB > 0.0f && pCB > 0.0f && pCA > 0.0f) {
            const float w1 = pCB / c[15];
            const float w2 = pCA / c[15];
            const float w3 = (1.0f - w1) - w2;
            const float zp = (w1*c[6] + w2*c[7]) + w3*c[8];
            const float z  = 1.0f / zp;                // ptsZ
            if (z >= zinit) {
                const int fid = sfid[i];
                // argmax first-max == max z, lowest face id on exact tie
                if (z > best || (z == best && fid < wfid)) { best = z; wfid = fid; wslot = i; }
            }
        }
    }
    sh_best[grp][col] = best;
    sh_fid [grp][col] = wfid;
    sh_slot[grp][col] = wslot;
    __syncthreads();

    // combine 4 groups + epilogue: threads 0..255 (one per column)
    if (t < 256) {
        best = -INFINITY; wfid = INT_MAX; wslot = 0;
        #pragma unroll
        for (int g = 0; g < NSPLIT; ++g) {
            const float z = sh_best[g][t];
            const int   f = sh_fid [g][t];
            if (z > best || (z == best && f < wfid)) { best = z; wfid = f; wslot = sh_slot[g][t]; }
        }

        const bool  hit = (best > -INFINITY);
        const float hf  = hit ? 1.0f : 0.0f;
        float r0 = 0.0f, r1 = 0.0f, r2 = 0.0f;

        if (hit) {
            const float* c = &fdl[wslot * PFSZ];
            const float pCB = (px - c[4])*(c[3] - c[5]) - (py - c[5])*(c[2] - c[4]);
            const float pCA = (px - c[0])*(c[5] - c[1]) - (py - c[1])*(c[4] - c[0]);
            const float w1 = pCB / c[15];
            const float w2 = pCA / c[15];
            const float w3 = (1.0f - w1) - w2;
            const float p3 = (w1*c[9]  + w2*c[11]) + w3*c[13];  // uv.x * zinv interp
            const float p4 = (w1*c[10] + w2*c[12]) + w3*c[14];  // uv.y * zinv interp
            const float p8 = (w1*c[6]  + w2*c[7])  + w3*c[8];   // zinv interp
            const float Zw = 1.0f / p8;
            const float gx = p3 * Zw;
            const float gy = p4 * Zw;

            // bilinear_sample(uvmap, gx, gy), zero padding, W=H=256
            const float x = ((gx + 1.0f)*256.0f - 1.0f)*0.5f;
            const float y = ((gy + 1.0f)*256.0f - 1.0f)*0.5f;
            const float x0f = floorf(x), y0f = floorf(y);
            const float x1f = x0f + 1.0f, y1f = y0f + 1.0f;
            const float wx1 = x - x0f, wx0 = 1.0f - wx1;
            const float wy1 = y - y0f, wy0 = 1.0f - wy1;
            const float w00 = wx0*wy0, w10 = wx1*wy0, w01 = wx0*wy1, w11 = wx1*wy1;

            // corner order matches reference add order
            {
                const bool v = (x0f >= 0.0f) && (x0f <= 255.0f) && (y0f >= 0.0f) && (y0f <= 255.0f);
                const int ix = (int)fminf(fmaxf(x0f, 0.0f), 255.0f);
                const int iy = (int)fminf(fmaxf(y0f, 0.0f), 255.0f);
                const int o  = iy*256 + ix;
                const float g0 = v ? uvmap[o]          : 0.0f;
                const float g1 = v ? uvmap[65536 + o]  : 0.0f;
                const float g2 = v ? uvmap[131072 + o] : 0.0f;
                r0 = r0 + g0*w00; r1 = r1 + g1*w00; r2 = r2 + g2*w00;
            }
            {
                const bool v = (x1f >= 0.0f) && (x1f <= 255.0f) && (y0f >= 0.0f) && (y0f <= 255.0f);
                const int ix = (int)fminf(fmaxf(x1f, 0.0f), 255.0f);
                const int iy = (int)fminf(fmaxf(y0f, 0.0f), 255.0f);
                const int o  = iy*256 + ix;
                const float g0 = v ? uvmap[o]          : 0.0f;
                const float g1 = v ? uvmap[65536 + o]  : 0.0f;
                const float g2 = v ? uvmap[131072 + o] : 0.0f;
                r0 = r0 + g0*w10; r1 = r1 + g1*w10; r2 = r2 + g2*w10;
            }
            {
                const bool v = (x0f >= 0.0f) && (x0f <= 255.0f) && (y1f >= 0.0f) && (y1f <= 255.0f);
                const int ix = (int)fminf(fmaxf(x0f, 0.0f), 255.0f);
                const int iy = (int)fminf(fmaxf(y1f, 0.0f), 255.0f);
                const int o  = iy*256 + ix;
                const float g0 = v ? uvmap[o]          : 0.0f;
                const float g1 = v ? uvmap[65536 + o]  : 0.0f;
                const float g2 = v ? uvmap[131072 + o] : 0.0f;
                r0 = r0 + g0*w01; r1 = r1 + g1*w01; r2 = r2 + g2*w01;
            }
            {
                const bool v = (x1f >= 0.0f) && (x1f <= 255.0f) && (y1f >= 0.0f) && (y1f <= 255.0f);
                const int ix = (int)fminf(fmaxf(x1f, 0.0f), 255.0f);
                const int iy = (int)fminf(fmaxf(y1f, 0.0f), 255.0f);
                const int o  = iy*256 + ix;
                const float g0 = v ? uvmap[o]          : 0.0f;
                const float g1 = v ? uvmap[65536 + o]  : 0.0f;
                const float g2 = v ? uvmap[131072 + o] : 0.0f;
                r0 = r0 + g0*w11; r1 = r1 + g1*w11; r2 = r2 + g2*w11;
            }
        }

        const int pix = row*256 + t;
        out[           pix] = r0*hf;
        out[ 65536 +   pix] = r1*hf;
        out[131072 +   pix] = r2*hf;
        out[196608 +   pix] = hf;
    }
}

extern "C" void kernel_launch(void* const* d_in, const int* in_sizes, int n_in,
                              void* d_out, int out_size, void* d_ws, size_t ws_size,
                              hipStream_t stream) {
    const float* vertices = (const float*)d_in[0];
    const int*   faces    = (const int*)  d_in[1];
    const float* uv       = (const float*)d_in[2];
    const int*   uvfaces  = (const int*)  d_in[3];
    const float* uvmap    = (const float*)d_in[4];
    float*       out      = (float*)d_out;

    char* ws = (char*)d_ws;
    float* fdG    = (float*)(ws + 0);
    float* zinitp = (float*)(ws + 20480);
    int*   rowPtr = (int*)  (ws + 20544);
    int*   ids    = (int*)  (ws + 22528);

    prep_kernel  <<<1,   256,  0, stream>>>(vertices, faces, uv, uvfaces,
                                            fdG, zinitp, rowPtr, ids);
    raster_kernel<<<SIZE, 1024, 0, stream>>>(fdG, zinitp, rowPtr, ids, uvmap, out);
}

// Round 5
// 74.485 us; speedup vs baseline: 1.3255x; 1.3255x over previous
//
#include <hip/hip_runtime.h>
#include <math.h>
#include <limits.h>

#define SIZE   256
#define NFACES 256
#define NVERTS 1024
#define NSPLIT 8     // 8 face-groups of 128 columns each (block = 1024 threads)

// LDS face record, 5 x float4 per face:
// q0: ax ay bx by | q1: cx cy xmin xmax | q2: z0i z1i z2i A
// q3: u0x u0y u1x u1y | q4: u2x u2y 0 0

// grid (2, 256): blockIdx.y = row, blockIdx.x = column half (128 cols).
// 512 blocks x 16 waves = 2 blocks/CU = 32 waves/CU (max occupancy).
// Phase 1 (threads<256): prep face t, cull A<1e-9 (=> cover false exactly) and
//   y-bbox vs this row with 1e-4 margin (fp edge noise <= ~5e-7*scale, cannot
//   flip the reference sign test). Stable ballot compaction keeps ascending
//   face order.
// Phase 2: group g=t>>7 tests its chunk of the compacted list for column
//   (t&127)+128*half, with wave-uniform x-bbox cull (same margin argument).
// Winner: max z, lowest face id on exact tie == numpy argmax first-max.
__global__ __launch_bounds__(1024) void render_kernel(
    const float* __restrict__ vertices,  // (1024,3)
    const int*   __restrict__ faces,     // (256,3)
    const float* __restrict__ uv,        // (1024,2)
    const int*   __restrict__ uvfaces,   // (256,3)
    const float* __restrict__ uvmap,     // (3,256,256)
    float* __restrict__ out)             // (4,256,256)
{
#pragma clang fp contract(off)
    __shared__ float4 fdl[NFACES * 5];
    __shared__ int    sfid[NFACES];
    __shared__ float  sh_best[NSPLIT][128];
    __shared__ int    sh_fid [NSPLIT][128];
    __shared__ int    sh_slot[NSPLIT][128];
    __shared__ float  wred[16];
    __shared__ int    wcnt[4];

    const int t    = threadIdx.x;
    const int lane = t & 63;
    const int wv   = t >> 6;                 // wave 0..15
    const int half = blockIdx.x;             // 0..1
    const int row  = blockIdx.y;             // 0..255
    const int col  = (t & 127) + 128 * half;
    const int grp  = t >> 7;                 // 0..7

    // pts[i,j] = (lin[j], lin[255-i]); linspace f64 -> f32 (numpy style)
    const float px = (float)(-1.0 + (double)col         * (2.0/255.0));
    const float py = (float)(-1.0 + (double)(255 - row) * (2.0/255.0));

    // ---- zinit partial: wave min of one vertex z per thread ----
    {
        float m = vertices[3*t + 2];
        for (int off = 32; off > 0; off >>= 1) m = fminf(m, __shfl_down(m, off));
        if (lane == 0) wred[wv] = m;
    }

    // ---- per-face prep in registers: thread t < 256 handles face t ----
    float4 q0, q1, q2, q3, q4;
    bool keep = false;
    int  rank = 0;
    if (t < NFACES) {
        const int i0 = faces[3*t+0], i1 = faces[3*t+1], i2 = faces[3*t+2];
        const float ax = vertices[3*i0+0], ay = vertices[3*i0+1], az = vertices[3*i0+2];
        const float bx = vertices[3*i1+0], by = vertices[3*i1+1], bz = vertices[3*i1+2];
        const float cx = vertices[3*i2+0], cy = vertices[3*i2+1], cz = vertices[3*i2+2];
        // A = area2d; same fp32 expression as face-normal z =>
        // cullmask & (A>=1e-9) == (A>=1e-9); A>=1e-9 also => Asafe==A
        const float A = (bx-ax)*(cy-ay) - (by-ay)*(cx-ax);
        const float ymin = fminf(fminf(ay,by),cy);
        const float ymax = fmaxf(fmaxf(ay,by),cy);
        keep = (A >= 1e-9f) && (py > ymin - 1e-4f) && (py < ymax + 1e-4f);
        const unsigned long long bmask = __ballot(keep);
        rank = __popcll(bmask & ((1ull << lane) - 1ull));
        if (lane == 0) wcnt[wv] = (int)__popcll(bmask);
        if (keep) {
            const float z0i = 1.0f/az, z1i = 1.0f/bz, z2i = 1.0f/cz;
            const int j0 = uvfaces[3*t+0], j1 = uvfaces[3*t+1], j2 = uvfaces[3*t+2];
            q0 = make_float4(ax, ay, bx, by);
            q1 = make_float4(cx, cy, fminf(fminf(ax,bx),cx), fmaxf(fmaxf(ax,bx),cx));
            q2 = make_float4(z0i, z1i, z2i, A);
            q3 = make_float4((uv[2*j0+0]*2.0f - 1.0f) * z0i,
                             (uv[2*j0+1]*2.0f - 1.0f) * z0i,
                             (uv[2*j1+0]*2.0f - 1.0f) * z1i,
                             (uv[2*j1+1]*2.0f - 1.0f) * z1i);
            q4 = make_float4((uv[2*j2+0]*2.0f - 1.0f) * z2i,
                             (uv[2*j2+1]*2.0f - 1.0f) * z2i, 0.0f, 0.0f);
        }
    }
    __syncthreads();   // wred + wcnt published

    float zinit;
    {
        float mm = wred[0];
        #pragma unroll
        for (int i = 1; i < 16; ++i) mm = fminf(mm, wred[i]);
        zinit = mm;    // every thread computes; no extra barrier
    }
    const int nv = wcnt[0] + wcnt[1] + wcnt[2] + wcnt[3];

    if (t < NFACES && keep) {
        int base = 0;
        #pragma unroll
        for (int w = 0; w < 4; ++w) if (w < wv) base += wcnt[w];
        const int slot = base + rank;
        sfid[slot] = t;
        fdl[slot*5+0] = q0; fdl[slot*5+1] = q1; fdl[slot*5+2] = q2;
        fdl[slot*5+3] = q3; fdl[slot*5+4] = q4;
    }
    __syncthreads();   // fdl + sfid published

    // wave-uniform x-span (each wave = 64 contiguous columns)
    const int   c0   = ((t >> 6) & 1) * 64 + 128 * half;
    const float pxlo = (float)(-1.0 + (double)c0        * (2.0/255.0));
    const float pxhi = (float)(-1.0 + (double)(c0 + 63) * (2.0/255.0));

    const int cs = (nv + NSPLIT - 1) / NSPLIT;
    int f0 = grp * cs; if (f0 > nv) f0 = nv;
    int f1 = f0 + cs;  if (f1 > nv) f1 = nv;

    float best  = -INFINITY;
    int   wfid  = INT_MAX;
    int   wslot = 0;
    for (int i = f0; i < f1; ++i) {
        const float4 c1 = fdl[i*5+1];        // cx cy xmin xmax
        // wave-uniform x-bbox cull (1e-4 margin, validated in R4)
        if (c1.w + 1e-4f < pxlo || c1.z - 1e-4f > pxhi) continue;
        const float4 c0q = fdl[i*5+0];       // ax ay bx by
        const float pAB = (px - c0q.z)*(c0q.y - c0q.w) - (py - c0q.w)*(c0q.x - c0q.z);
        const float pCB = (px - c1.x)*(c0q.w - c1.y)   - (py - c1.y)*(c0q.z - c1.x);
        const float pCA = (px - c0q.x)*(c1.y - c0q.y)  - (py - c0q.y)*(c1.x - c0q.x);
        if (pAB > 0.0f && pCB > 0.0f && pCA > 0.0f) {
            const float4 c2 = fdl[i*5+2];    // z0i z1i z2i A
            const float w1 = pCB / c2.w;
            const float w2 = pCA / c2.w;
            const float w3 = (1.0f - w1) - w2;
            const float zp = (w1*c2.x + w2*c2.y) + w3*c2.z;
            const float z  = 1.0f / zp;                // ptsZ
            if (z >= zinit) {
                const int fid = sfid[i];
                if (z > best || (z == best && fid < wfid)) { best = z; wfid = fid; wslot = i; }
            }
        }
    }
    sh_best[grp][t & 127] = best;
    sh_fid [grp][t & 127] = wfid;
    sh_slot[grp][t & 127] = wslot;
    __syncthreads();

    // ---- combine 8 groups + epilogue: threads 0..127 (one per column) ----
    if (t < 128) {
        best = -INFINITY; wfid = INT_MAX; wslot = 0;
        #pragma unroll
        for (int g = 0; g < NSPLIT; ++g) {   // chunks ascend in face id; strict >
            const float z = sh_best[g][t];   // + fid tie-break == first-max
            const int   f = sh_fid [g][t];
            if (z > best || (z == best && f < wfid)) { best = z; wfid = f; wslot = sh_slot[g][t]; }
        }

        const bool  hit = (best > -INFINITY);
        const float hf  = hit ? 1.0f : 0.0f;
        float r0 = 0.0f, r1 = 0.0f, r2 = 0.0f;

        if (hit) {
            const float4 c0q = fdl[wslot*5+0];
            const float4 c1  = fdl[wslot*5+1];
            const float4 c2  = fdl[wslot*5+2];
            const float4 c3  = fdl[wslot*5+3];
            const float4 c4  = fdl[wslot*5+4];
            const float pCB = (px - c1.x)*(c0q.w - c1.y)  - (py - c1.y)*(c0q.z - c1.x);
            const float pCA = (px - c0q.x)*(c1.y - c0q.y) - (py - c0q.y)*(c1.x - c0q.x);
            const float w1 = pCB / c2.w;
            const float w2 = pCA / c2.w;
            const float w3 = (1.0f - w1) - w2;
            const float p3 = (w1*c3.x + w2*c3.z) + w3*c4.x;  // uv.x * zinv interp
            const float p4 = (w1*c3.y + w2*c3.w) + w3*c4.y;  // uv.y * zinv interp
            const float p8 = (w1*c2.x + w2*c2.y) + w3*c2.z;  // zinv interp
            const float Zw = 1.0f / p8;
            const float gx = p3 * Zw;
            const float gy = p4 * Zw;

            // bilinear_sample(uvmap, gx, gy), zero padding, W=H=256
            const float x = ((gx + 1.0f)*256.0f - 1.0f)*0.5f;
            const float y = ((gy + 1.0f)*256.0f - 1.0f)*0.5f;
            const float x0f = floorf(x), y0f = floorf(y);
            const float x1f = x0f + 1.0f, y1f = y0f + 1.0f;
            const float wx1 = x - x0f, wx0 = 1.0f - wx1;
            const float wy1 = y - y0f, wy0 = 1.0f - wy1;
            const float w00 = wx0*wy0, w10 = wx1*wy0, w01 = wx0*wy1, w11 = wx1*wy1;

            // corner order matches reference add order
            {
                const bool v = (x0f >= 0.0f) && (x0f <= 255.0f) && (y0f >= 0.0f) && (y0f <= 255.0f);
                const int ix = (int)fminf(fmaxf(x0f, 0.0f), 255.0f);
                const int iy = (int)fminf(fmaxf(y0f, 0.0f), 255.0f);
                const int o  = iy*256 + ix;
                const float g0 = v ? uvmap[o]          : 0.0f;
                const float g1 = v ? uvmap[65536 + o]  : 0.0f;
                const float g2 = v ? uvmap[131072 + o] : 0.0f;
                r0 = r0 + g0*w00; r1 = r1 + g1*w00; r2 = r2 + g2*w00;
            }
            {
                const bool v = (x1f >= 0.0f) && (x1f <= 255.0f) && (y0f >= 0.0f) && (y0f <= 255.0f);
                const int ix = (int)fminf(fmaxf(x1f, 0.0f), 255.0f);
                const int iy = (int)fminf(fmaxf(y0f, 0.0f), 255.0f);
                const int o  = iy*256 + ix;
                const float g0 = v ? uvmap[o]          : 0.0f;
                const float g1 = v ? uvmap[65536 + o]  : 0.0f;
                const float g2 = v ? uvmap[131072 + o] : 0.0f;
                r0 = r0 + g0*w10; r1 = r1 + g1*w10; r2 = r2 + g2*w10;
            }
            {
                const bool v = (x0f >= 0.0f) && (x0f <= 255.0f) && (y1f >= 0.0f) && (y1f <= 255.0f);
                const int ix = (int)fminf(fmaxf(x0f, 0.0f), 255.0f);
                const int iy = (int)fminf(fmaxf(y1f, 0.0f), 255.0f);
                const int o  = iy*256 + ix;
                const float g0 = v ? uvmap[o]          : 0.0f;
                const float g1 = v ? uvmap[65536 + o]  : 0.0f;
                const float g2 = v ? uvmap[131072 + o] : 0.0f;
                r0 = r0 + g0*w01; r1 = r1 + g1*w01; r2 = r2 + g2*w01;
            }
            {
                const bool v = (x1f >= 0.0f) && (x1f <= 255.0f) && (y1f >= 0.0f) && (y1f <= 255.0f);
                const int ix = (int)fminf(fmaxf(x1f, 0.0f), 255.0f);
                const int iy = (int)fminf(fmaxf(y1f, 0.0f), 255.0f);
                const int o  = iy*256 + ix;
                const float g0 = v ? uvmap[o]          : 0.0f;
                const float g1 = v ? uvmap[65536 + o]  : 0.0f;
                const float g2 = v ? uvmap[131072 + o] : 0.0f;
                r0 = r0 + g0*w11; r1 = r1 + g1*w11; r2 = r2 + g2*w11;
            }
        }

        const int pix = row*256 + col;
        out[           pix] = r0*hf;
        out[ 65536 +   pix] = r1*hf;
        out[131072 +   pix] = r2*hf;
        out[196608 +   pix] = hf;
    }
}

extern "C" void kernel_launch(void* const* d_in, const int* in_sizes, int n_in,
                              void* d_out, int out_size, void* d_ws, size_t ws_size,
                              hipStream_t stream) {
    const float* vertices = (const float*)d_in[0];
    const int*   faces    = (const int*)  d_in[1];
    const float* uv       = (const float*)d_in[2];
    const int*   uvfaces  = (const int*)  d_in[3];
    const float* uvmap    = (const float*)d_in[4];
    float*       out      = (float*)d_out;

    dim3 grid(2, SIZE);
    render_kernel<<<grid, 1024, 0, stream>>>(vertices, faces, uv, uvfaces, uvmap, out);
}